// Round 7
// baseline (229.959 us; speedup 1.0000x reference)
//
#include <hip/hip_runtime.h>
#include <hip/hip_cooperative_groups.h>

namespace cg = cooperative_groups;

// Problem: d=64, nq=1024, nk=2048, h=64.
// Fused cooperative kernel, grid 512 x 256, LDS exactly 32 KB -> 2 blocks/CU.
// P1: qp/kp projections. P2: block (qt,kt): 64q x 64k score tile (4x4 reg
// tile), scores -> global, exp(s) regs -> LDS, PV partial -> part/lpart.
// P3: reduce 32 partials, /l, -> out. W2 read via wave-uniform global loads
// (s_load), not LDS, to keep LDS at 32 KB (64 KB/CU occupancy model!).

__global__ __launch_bounds__(256, 2) void fused_mlp_attn(
    const float* __restrict__ q, const float* __restrict__ key,
    const float* __restrict__ v,
    const float* __restrict__ W1, const float* __restrict__ b1,
    const float* __restrict__ W2, const float* __restrict__ b2p,
    float* __restrict__ out, float* __restrict__ scores,
    float* __restrict__ qp, float* __restrict__ kp,
    float* __restrict__ lpart, float* __restrict__ part)
{
  __shared__ float4 smem4[2048];      // 32 KB; aliased per phase
  float* smemf = (float*)smem4;
  cg::grid_group grid = cg::this_grid();
  const int t = threadIdx.x;
  const int bid = blockIdx.x;

  // ===================== P1: projections =====================
  for (int u = bid; u < 768; u += 512) {
    if (u < 256) {                    // qp tile: 64n x 4h
      const int nb = (u & 15) << 6;
      const int hb = (u >> 4) << 2;
      const int n = nb + (t & 63);
      const int h = hb + (t >> 6);    // wave-uniform
      const float* wr = W1 + h * 128;
      float acc = b1[h];
#pragma unroll
      for (int d = 0; d < 64; ++d) acc = fmaf(wr[d], q[(d << 10) + n], acc);
      smemf[((t & 63) << 2) + (t >> 6)] = acc;
      __syncthreads();
      qp[((nb + (t >> 2)) << 6) + hb + (t & 3)] = smemf[t];
    } else {                          // kp tile: 64m x 4h
      const int u2 = u - 256;
      const int mb = (u2 & 31) << 6;
      const int hb = (u2 >> 5) << 2;
      const int m = mb + (t & 63);
      const int h = hb + (t >> 6);
      const float* wr = W1 + h * 128 + 64;
      float acc = 0.f;
#pragma unroll
      for (int d = 0; d < 64; ++d) acc = fmaf(wr[d], key[(d << 11) + m], acc);
      smemf[((t & 63) << 2) + (t >> 6)] = acc;
      __syncthreads();
      kp[((mb + (t >> 2)) << 6) + hb + (t & 3)] = smemf[t];
    }
    __syncthreads();                  // tile buffer reuse across loop trips
  }
  grid.sync();

  // ===================== P2: scores + exp + PV =====================
  float4* qS = smem4;                 // 64q x 16 f4, col ^= ((row>>2)&15)
  float4* kS = smem4 + 1024;          // 64k x 16 f4, same swizzle
  const int qt = bid >> 5, kt = bid & 31;
  const int q0b = qt << 6, k0b = kt << 6;
  const float4* qp4 = (const float4*)qp;
  const float4* kp4 = (const float4*)kp;
#pragma unroll
  for (int i = 0; i < 4; ++i) {       // stage both tiles, coalesced
    const int idx = (i << 8) + t;
    const int row = idx >> 4, c = idx & 15;
    const int cs = c ^ ((row >> 2) & 15);
    qS[(row << 4) + cs] = qp4[((q0b + row) << 4) + c];
    kS[(row << 4) + cs] = kp4[((k0b + row) << 4) + c];
  }
  __syncthreads();

  const int lane = t & 63, wave = t >> 6;
  const int lq = lane >> 4, lk = lane & 15;
  const int ql0 = (wave << 4) + (lq << 2);   // block-local q row base
  const int sq = (wave << 2) | lq;           // ((ql0>>2)&15)
  const int kl0 = lk << 2;
  const float4* w24 = (const float4*)W2;     // uniform -> s_load

  float4 acc0 = {0,0,0,0}, acc1 = {0,0,0,0};
  float4 acc2 = {0,0,0,0}, acc3 = {0,0,0,0}; // accI = q-row I x k j=0..3

#pragma unroll 4
  for (int h4 = 0; h4 < 16; ++h4) {
    const float4 wv = w24[h4];
    const int qc = h4 ^ sq, kc = h4 ^ lk;
    const float4 q0f = qS[((ql0 + 0) << 4) + qc];
    const float4 q1f = qS[((ql0 + 1) << 4) + qc];
    const float4 q2f = qS[((ql0 + 2) << 4) + qc];
    const float4 q3f = qS[((ql0 + 3) << 4) + qc];
    const float4 k0f = kS[((kl0 + 0) << 4) + kc];
    const float4 k1f = kS[((kl0 + 1) << 4) + kc];
    const float4 k2f = kS[((kl0 + 2) << 4) + kc];
    const float4 k3f = kS[((kl0 + 3) << 4) + kc];
#define HC(C)                                                        \
    acc0.x = fmaf(wv.C, fmaxf(q0f.C + k0f.C, 0.f), acc0.x);          \
    acc0.y = fmaf(wv.C, fmaxf(q0f.C + k1f.C, 0.f), acc0.y);          \
    acc0.z = fmaf(wv.C, fmaxf(q0f.C + k2f.C, 0.f), acc0.z);          \
    acc0.w = fmaf(wv.C, fmaxf(q0f.C + k3f.C, 0.f), acc0.w);          \
    acc1.x = fmaf(wv.C, fmaxf(q1f.C + k0f.C, 0.f), acc1.x);          \
    acc1.y = fmaf(wv.C, fmaxf(q1f.C + k1f.C, 0.f), acc1.y);          \
    acc1.z = fmaf(wv.C, fmaxf(q1f.C + k2f.C, 0.f), acc1.z);          \
    acc1.w = fmaf(wv.C, fmaxf(q1f.C + k3f.C, 0.f), acc1.w);          \
    acc2.x = fmaf(wv.C, fmaxf(q2f.C + k0f.C, 0.f), acc2.x);          \
    acc2.y = fmaf(wv.C, fmaxf(q2f.C + k1f.C, 0.f), acc2.y);          \
    acc2.z = fmaf(wv.C, fmaxf(q2f.C + k2f.C, 0.f), acc2.z);          \
    acc2.w = fmaf(wv.C, fmaxf(q2f.C + k3f.C, 0.f), acc2.w);          \
    acc3.x = fmaf(wv.C, fmaxf(q3f.C + k0f.C, 0.f), acc3.x);          \
    acc3.y = fmaf(wv.C, fmaxf(q3f.C + k1f.C, 0.f), acc3.y);          \
    acc3.z = fmaf(wv.C, fmaxf(q3f.C + k2f.C, 0.f), acc3.z);          \
    acc3.w = fmaf(wv.C, fmaxf(q3f.C + k3f.C, 0.f), acc3.w);
    HC(x) HC(y) HC(z) HC(w)
#undef HC
  }

  // Epilogue: bias + scores store + exp (kept in regs) + lpart
  const float b2v = b2p[0];
  float4* sc4 = (float4*)scores;
  const int kcol = (k0b >> 2) + lk;
  float4 e0, e1, e2, e3;
#define ROW_OUT(I, ACC, E) {                                         \
    float4 s = ACC;                                                  \
    s.x += b2v; s.y += b2v; s.z += b2v; s.w += b2v;                  \
    sc4[((q0b + ql0 + I) << 9) + kcol] = s;                          \
    E.x = __expf(s.x); E.y = __expf(s.y);                            \
    E.z = __expf(s.z); E.w = __expf(s.w);                            \
    float e = E.x + E.y + E.z + E.w;                                 \
    e += __shfl_xor(e, 1); e += __shfl_xor(e, 2);                    \
    e += __shfl_xor(e, 4); e += __shfl_xor(e, 8);                    \
    if (lk == 0) lpart[(kt << 10) + q0b + ql0 + I] = e; }
  ROW_OUT(0, acc0, e0) ROW_OUT(1, acc1, e1)
  ROW_OUT(2, acc2, e2) ROW_OUT(3, acc3, e3)
#undef ROW_OUT

  // ---- PV inside the same block: exp tile regs -> LDS, V -> LDS ----
  __syncthreads();                    // all qS/kS reads done
  float4* pS4 = smem4;                // 64n x 16 f4, unswizzled
  float4* vtS4 = smem4 + 1024;        // 64m x 16 f4 transposed V, swizzled
  float* vtSf = (float*)vtS4;
  pS4[((ql0 + 0) << 4) + lk] = e0;
  pS4[((ql0 + 1) << 4) + lk] = e1;
  pS4[((ql0 + 2) << 4) + lk] = e2;
  pS4[((ql0 + 3) << 4) + lk] = e3;
  const float4* v4 = (const float4*)v;
  const int mc4 = kt << 4;
#pragma unroll
  for (int i = 0; i < 4; ++i) {       // stage V chunk transposed
    const int idx = (i << 8) + t;
    const int dd = idx >> 4, c = idx & 15;
    const float4 val = v4[(dd << 9) + mc4 + c];
    const int co = (((dd >> 2) ^ c) << 2) + (dd & 3);
    vtSf[(c << 8) + co] = val.x;
    vtSf[(c << 8) + 64 + co] = val.y;
    vtSf[(c << 8) + 128 + co] = val.z;
    vtSf[(c << 8) + 192 + co] = val.w;
  }
  __syncthreads();

  {
    const int tn = t >> 3, td = t & 7;
    const int n0l = tn << 1, n1l = n0l + 1;
    float4 acc00 = {0,0,0,0}, acc01 = {0,0,0,0};
    float4 acc10 = {0,0,0,0}, acc11 = {0,0,0,0};

#define PV_STEP(J, AC) {                                       \
    const float4 b0 = vtS4[(m4 << 6) + (J << 4) + c0];         \
    const float4 b1 = vtS4[(m4 << 6) + (J << 4) + (c0 ^ 8)];   \
    acc00.x = fmaf(a0.AC, b0.x, acc00.x);                      \
    acc00.y = fmaf(a0.AC, b0.y, acc00.y);                      \
    acc00.z = fmaf(a0.AC, b0.z, acc00.z);                      \
    acc00.w = fmaf(a0.AC, b0.w, acc00.w);                      \
    acc01.x = fmaf(a0.AC, b1.x, acc01.x);                      \
    acc01.y = fmaf(a0.AC, b1.y, acc01.y);                      \
    acc01.z = fmaf(a0.AC, b1.z, acc01.z);                      \
    acc01.w = fmaf(a0.AC, b1.w, acc01.w);                      \
    acc10.x = fmaf(a1.AC, b0.x, acc10.x);                      \
    acc10.y = fmaf(a1.AC, b0.y, acc10.y);                      \
    acc10.z = fmaf(a1.AC, b0.z, acc10.z);                      \
    acc10.w = fmaf(a1.AC, b0.w, acc10.w);                      \
    acc11.x = fmaf(a1.AC, b1.x, acc11.x);                      \
    acc11.y = fmaf(a1.AC, b1.y, acc11.y);                      \
    acc11.z = fmaf(a1.AC, b1.z, acc11.z);                      \
    acc11.w = fmaf(a1.AC, b1.w, acc11.w);                      \
  }

#pragma unroll
    for (int m4 = 0; m4 < 16; ++m4) {
      const float4 a0 = pS4[(n0l << 4) + m4];
      const float4 a1 = pS4[(n1l << 4) + m4];
      const int c0 = td ^ m4;
      PV_STEP(0, x) PV_STEP(1, y) PV_STEP(2, z) PV_STEP(3, w)
    }
#undef PV_STEP

    float4* part4 = (float4*)part;
    const int pb0 = (kt << 14) + ((q0b + n0l) << 4);
    const int pb1 = (kt << 14) + ((q0b + n1l) << 4);
    part4[pb0 + td] = acc00;
    part4[pb0 + td + 8] = acc01;
    part4[pb1 + td] = acc10;
    part4[pb1 + td + 8] = acc11;
  }
  grid.sync();

  // ===================== P3: reduce -> out =====================
  {
    const int nl = t >> 7;            // 2 n per block
    const int tt = t & 127;
    const int g = tt >> 6;            // split the 32 partials in half
    const int d = tt & 63;
    const int n = (bid << 1) + nl;
    float s = 0.f;
#pragma unroll
    for (int ms = 0; ms < 16; ++ms)
      s += part[((g * 16 + ms) << 16) + (n << 6) + d];
    smemf[(nl << 7) + (g << 6) + d] = s;
    if (d == 0) {
      float lp = 0.f;
#pragma unroll
      for (int k2 = 0; k2 < 16; ++k2) lp += lpart[((g * 16 + k2) << 10) + n];
      smemf[512 + (nl << 1) + g] = lp;
    }
    __syncthreads();
    if (t < 128) {
      const int nl2 = t >> 6, d2 = t & 63;
      const int n2 = (bid << 1) + nl2;
      const float sum = smemf[(nl2 << 7) + d2] + smemf[(nl2 << 7) + 64 + d2];
      const float l = smemf[512 + (nl2 << 1)] + smemf[512 + (nl2 << 1) + 1];
      out[(d2 << 10) + n2] = sum / l;
    }
  }
}

// ======================= Fallback pipeline (R5, proven) =======================
__global__ __launch_bounds__(256) void k1_proj(
    const float* __restrict__ q, const float* __restrict__ k,
    const float* __restrict__ W1, const float* __restrict__ b1,
    float* __restrict__ qp, float* __restrict__ kp)
{
  __shared__ float tile[256];
  const int t = threadIdx.x;
  const int b = blockIdx.x;
  if (b < 256) {
    const int nb = (b & 15) << 6;
    const int hb = (b >> 4) << 2;
    const int n = nb + (t & 63);
    const int h = hb + (t >> 6);
    const float* wr = W1 + h * 128;
    float acc = b1[h];
#pragma unroll
    for (int d = 0; d < 64; ++d) acc = fmaf(wr[d], q[(d << 10) + n], acc);
    tile[((t & 63) << 2) + (t >> 6)] = acc;
    __syncthreads();
    qp[((nb + (t >> 2)) << 6) + hb + (t & 3)] = tile[t];
  } else {
    const int b2 = b - 256;
    const int mb = (b2 & 31) << 6;
    const int hb = (b2 >> 5) << 2;
    const int m = mb + (t & 63);
    const int h = hb + (t >> 6);
    const float* wr = W1 + h * 128 + 64;
    float acc = 0.f;
#pragma unroll
    for (int d = 0; d < 64; ++d) acc = fmaf(wr[d], k[(d << 11) + m], acc);
    tile[((t & 63) << 2) + (t >> 6)] = acc;
    __syncthreads();
    kp[((mb + (t >> 2)) << 6) + hb + (t & 3)] = tile[t];
  }
}

__global__ __launch_bounds__(256, 2) void k2_scores(
    const float* __restrict__ qp, const float* __restrict__ kp,
    const float* __restrict__ W2, const float* __restrict__ b2p,
    float* __restrict__ scores, float* __restrict__ lpart)
{
  __shared__ float4 qS[1024];
  __shared__ float4 kS[1024];
  const int t = threadIdx.x;
  const int qt = blockIdx.x >> 5;
  const int kt = blockIdx.x & 31;
  const int q0b = qt << 6, k0b = kt << 6;
  const float4* qp4 = (const float4*)qp;
  const float4* kp4 = (const float4*)kp;
#pragma unroll
  for (int i = 0; i < 4; ++i) {
    const int idx = (i << 8) + t;
    const int row = idx >> 4, c = idx & 15;
    const int cs = c ^ ((row >> 2) & 15);
    qS[(row << 4) + cs] = qp4[((q0b + row) << 4) + c];
    kS[(row << 4) + cs] = kp4[((k0b + row) << 4) + c];
  }
  __syncthreads();

  const int lane = t & 63, wave = t >> 6;
  const int lq = lane >> 4, lk = lane & 15;
  const int ql0 = (wave << 4) + (lq << 2);
  const int sq = (wave << 2) | lq;
  const int kl0 = lk << 2;
  const float4* w24 = (const float4*)W2;

  float4 acc0 = {0,0,0,0}, acc1 = {0,0,0,0};
  float4 acc2 = {0,0,0,0}, acc3 = {0,0,0,0};

#pragma unroll 4
  for (int h4 = 0; h4 < 16; ++h4) {
    const float4 wv = w24[h4];
    const int qc = h4 ^ sq, kc = h4 ^ lk;
    const float4 q0f = qS[((ql0 + 0) << 4) + qc];
    const float4 q1f = qS[((ql0 + 1) << 4) + qc];
    const float4 q2f = qS[((ql0 + 2) << 4) + qc];
    const float4 q3f = qS[((ql0 + 3) << 4) + qc];
    const float4 k0f = kS[((kl0 + 0) << 4) + kc];
    const float4 k1f = kS[((kl0 + 1) << 4) + kc];
    const float4 k2f = kS[((kl0 + 2) << 4) + kc];
    const float4 k3f = kS[((kl0 + 3) << 4) + kc];
#define HC(C)                                                        \
    acc0.x = fmaf(wv.C, fmaxf(q0f.C + k0f.C, 0.f), acc0.x);          \
    acc0.y = fmaf(wv.C, fmaxf(q0f.C + k1f.C, 0.f), acc0.y);          \
    acc0.z = fmaf(wv.C, fmaxf(q0f.C + k2f.C, 0.f), acc0.z);          \
    acc0.w = fmaf(wv.C, fmaxf(q0f.C + k3f.C, 0.f), acc0.w);          \
    acc1.x = fmaf(wv.C, fmaxf(q1f.C + k0f.C, 0.f), acc1.x);          \
    acc1.y = fmaf(wv.C, fmaxf(q1f.C + k1f.C, 0.f), acc1.y);          \
    acc1.z = fmaf(wv.C, fmaxf(q1f.C + k2f.C, 0.f), acc1.z);          \
    acc1.w = fmaf(wv.C, fmaxf(q1f.C + k3f.C, 0.f), acc1.w);          \
    acc2.x = fmaf(wv.C, fmaxf(q2f.C + k0f.C, 0.f), acc2.x);          \
    acc2.y = fmaf(wv.C, fmaxf(q2f.C + k1f.C, 0.f), acc2.y);          \
    acc2.z = fmaf(wv.C, fmaxf(q2f.C + k2f.C, 0.f), acc2.z);          \
    acc2.w = fmaf(wv.C, fmaxf(q2f.C + k3f.C, 0.f), acc2.w);          \
    acc3.x = fmaf(wv.C, fmaxf(q3f.C + k0f.C, 0.f), acc3.x);          \
    acc3.y = fmaf(wv.C, fmaxf(q3f.C + k1f.C, 0.f), acc3.y);          \
    acc3.z = fmaf(wv.C, fmaxf(q3f.C + k2f.C, 0.f), acc3.z);          \
    acc3.w = fmaf(wv.C, fmaxf(q3f.C + k3f.C, 0.f), acc3.w);
    HC(x) HC(y) HC(z) HC(w)
#undef HC
  }

  const float b2v = b2p[0];
  float4* sc4 = (float4*)scores;
  const int kcol = (k0b >> 2) + lk;
#define ROW_OUT(I, ACC) {                                            \
    float4 s = ACC;                                                  \
    s.x += b2v; s.y += b2v; s.z += b2v; s.w += b2v;                  \
    sc4[((q0b + ql0 + I) << 9) + kcol] = s;                          \
    float e = __expf(s.x) + __expf(s.y) + __expf(s.z) + __expf(s.w); \
    e += __shfl_xor(e, 1); e += __shfl_xor(e, 2);                    \
    e += __shfl_xor(e, 4); e += __shfl_xor(e, 8);                    \
    if (lk == 0) lpart[(kt << 10) + q0b + ql0 + I] = e; }
  ROW_OUT(0, acc0) ROW_OUT(1, acc1) ROW_OUT(2, acc2) ROW_OUT(3, acc3)
#undef ROW_OUT
}

__global__ __launch_bounds__(256, 2) void k3_pv(
    const float* __restrict__ scores, const float* __restrict__ v,
    float* __restrict__ part)
{
  __shared__ float4 pS4[1024];
  __shared__ float4 vtS4[1024];
  float* vtSf = (float*)vtS4;
  const int t = threadIdx.x;
  const int nt = blockIdx.x >> 5;
  const int ms = blockIdx.x & 31;
  const int n0b = nt << 6;
  const int mc4 = ms << 4;

  const float4* s4 = (const float4*)scores;
  const float4* v4 = (const float4*)v;
#pragma unroll
  for (int i = 0; i < 4; ++i) {
    const int idx = (i << 8) + t;
    const int n = idx >> 4, c = idx & 15;
    float4 val = s4[((n0b + n) << 9) + mc4 + c];
    val.x = __expf(val.x); val.y = __expf(val.y);
    val.z = __expf(val.z); val.w = __expf(val.w);
    pS4[(n << 4) + c] = val;
  }
#pragma unroll
  for (int i = 0; i < 4; ++i) {
    const int idx = (i << 8) + t;
    const int dd = idx >> 4, c = idx & 15;
    const float4 val = v4[(dd << 9) + mc4 + c];
    const int co = (((dd >> 2) ^ c) << 2) + (dd & 3);
    vtSf[(c << 8) + co] = val.x;
    vtSf[(c << 8) + 64 + co] = val.y;
    vtSf[(c << 8) + 128 + co] = val.z;
    vtSf[(c << 8) + 192 + co] = val.w;
  }
  __syncthreads();

  const int tn = t >> 3, td = t & 7;
  const int n0l = tn << 1, n1l = n0l + 1;
  float4 acc00 = {0,0,0,0}, acc01 = {0,0,0,0};
  float4 acc10 = {0,0,0,0}, acc11 = {0,0,0,0};

#define PV_STEP(J, AC) {                                       \
    const float4 b0 = vtS4[(m4 << 6) + (J << 4) + c0];         \
    const float4 b1 = vtS4[(m4 << 6) + (J << 4) + (c0 ^ 8)];   \
    acc00.x = fmaf(a0.AC, b0.x, acc00.x);                      \
    acc00.y = fmaf(a0.AC, b0.y, acc00.y);                      \
    acc00.z = fmaf(a0.AC, b0.z, acc00.z);                      \
    acc00.w = fmaf(a0.AC, b0.w, acc00.w);                      \
    acc01.x = fmaf(a0.AC, b1.x, acc01.x);                      \
    acc01.y = fmaf(a0.AC, b1.y, acc01.y);                      \
    acc01.z = fmaf(a0.AC, b1.z, acc01.z);                      \
    acc01.w = fmaf(a0.AC, b1.w, acc01.w);                      \
    acc10.x = fmaf(a1.AC, b0.x, acc10.x);                      \
    acc10.y = fmaf(a1.AC, b0.y, acc10.y);                      \
    acc10.z = fmaf(a1.AC, b0.z, acc10.z);                      \
    acc10.w = fmaf(a1.AC, b0.w, acc10.w);                      \
    acc11.x = fmaf(a1.AC, b1.x, acc11.x);                      \
    acc11.y = fmaf(a1.AC, b1.y, acc11.y);                      \
    acc11.z = fmaf(a1.AC, b1.z, acc11.z);                      \
    acc11.w = fmaf(a1.AC, b1.w, acc11.w);                      \
  }

#pragma unroll
  for (int m4 = 0; m4 < 16; ++m4) {
    const float4 a0 = pS4[(n0l << 4) + m4];
    const float4 a1 = pS4[(n1l << 4) + m4];
    const int c0 = td ^ m4;
    PV_STEP(0, x) PV_STEP(1, y) PV_STEP(2, z) PV_STEP(3, w)
  }
#undef PV_STEP

  float4* part4 = (float4*)part;
  const int pb0 = (ms << 14) + ((n0b + n0l) << 4);
  const int pb1 = (ms << 14) + ((n0b + n1l) << 4);
  part4[pb0 + td] = acc00;
  part4[pb0 + td + 8] = acc01;
  part4[pb1 + td] = acc10;
  part4[pb1 + td + 8] = acc11;
}

__global__ __launch_bounds__(256) void k4_reduce(
    const float* __restrict__ part, const float* __restrict__ lpart,
    float* __restrict__ out)
{
  __shared__ float oS[256];
  const int t = threadIdx.x;
  const int nb = blockIdx.x << 2;
  const int nl = t >> 6, d = t & 63;
  const int n = nb + nl;
  float sum = 0.f;
#pragma unroll
  for (int ms = 0; ms < 32; ++ms)
    sum += part[(ms << 16) + (n << 6) + d];
  float l = 0.f;
#pragma unroll
  for (int kt = 0; kt < 32; ++kt)
    l += lpart[(kt << 10) + n];
  oS[(nl << 6) + d] = sum / l;
  __syncthreads();
  const int d2 = t >> 2, n2 = t & 3;
  out[(d2 << 10) + nb + n2] = oS[(n2 << 6) + d2];
}

extern "C" void kernel_launch(void* const* d_in, const int* in_sizes, int n_in,
                              void* d_out, int out_size, void* d_ws, size_t ws_size,
                              hipStream_t stream) {
  const float* query = (const float*)d_in[0];
  const float* key   = (const float*)d_in[1];
  const float* value = (const float*)d_in[2];
  const float* W1    = (const float*)d_in[3];
  const float* b1    = (const float*)d_in[4];
  const float* W2    = (const float*)d_in[5];
  const float* b2    = (const float*)d_in[6];

  float* out    = (float*)d_out;       // (1,64,1024)
  float* scores = out + 65536;         // (1,1024,2048)

  float* ws    = (float*)d_ws;
  float* qp    = ws;                   // 1024*64
  float* kp    = ws + 65536;           // 2048*64
  float* lpart = ws + 196608;          // 32 x 1024
  float* part  = ws + 229376;          // 32 x 1024 x 64

  // Host-side co-residency check (capture-safe; baked into graph).
  int occ = 0, ncu = 0, dev = 0;
  hipGetDevice(&dev);
  hipDeviceGetAttribute(&ncu, hipDeviceAttributeMultiprocessorCount, dev);
  hipError_t oe = hipOccupancyMaxActiveBlocksPerMultiprocessor(
      &occ, fused_mlp_attn, 256, 0);

  if (oe == hipSuccess && occ * ncu >= 512) {
    void* args[] = {
      (void*)&query, (void*)&key, (void*)&value, (void*)&W1, (void*)&b1,
      (void*)&W2, (void*)&b2, (void*)&out, (void*)&scores,
      (void*)&qp, (void*)&kp, (void*)&lpart, (void*)&part
    };
    hipLaunchCooperativeKernel((void*)fused_mlp_attn, dim3(512), dim3(256),
                               args, 0, stream);
  } else {
    k1_proj<<<768, 256, 0, stream>>>(query, key, W1, b1, qp, kp);
    k2_scores<<<512, 256, 0, stream>>>(qp, kp, W2, b2, scores, lpart);
    k3_pv<<<512, 256, 0, stream>>>(scores, value, part);
    k4_reduce<<<256, 256, 0, stream>>>(part, lpart, out);
  }
}

// Round 8
// 177.485 us; speedup vs baseline: 1.2957x; 1.2957x over previous
//
#include <hip/hip_runtime.h>

// Problem: d=64, nq=1024, nk=2048, h=64.
// 4-kernel pipeline (cooperative fusion measured 14x slower - grid.sync cost).
// Measured context (R7): harness fixed overhead ~90 us (268MB ws poison fill
// 42.7us + fills/restores/dispatch gaps); kernels total ~10 us.
// ws layout (floats): qp[1024][64] @0, kp[2048][64] @65536,
//   lpart[32][1024] @196608, part[32][1024][64] @229376
// scores lives in d_out (out[65536] then scores[1024*2048]).

// ---------------- K1: projections ----------------
__global__ __launch_bounds__(256) void k1_proj(
    const float* __restrict__ q, const float* __restrict__ k,
    const float* __restrict__ W1, const float* __restrict__ b1,
    float* __restrict__ qp, float* __restrict__ kp)
{
  __shared__ float tile[256];
  const int t = threadIdx.x;
  const int b = blockIdx.x;
  if (b < 256) {                      // qp: 16 n-tiles x 16 h-tiles
    const int nb = (b & 15) << 6;
    const int hb = (b >> 4) << 2;
    const int n = nb + (t & 63);
    const int h = hb + (t >> 6);      // wave-uniform
    const float* wr = W1 + h * 128;
    float acc = b1[h];
#pragma unroll
    for (int d = 0; d < 64; ++d) acc = fmaf(wr[d], q[(d << 10) + n], acc);
    tile[((t & 63) << 2) + (t >> 6)] = acc;
    __syncthreads();
    qp[((nb + (t >> 2)) << 6) + hb + (t & 3)] = tile[t];
  } else {                            // kp: 32 m-tiles x 16 h-tiles
    const int b2 = b - 256;
    const int mb = (b2 & 31) << 6;
    const int hb = (b2 >> 5) << 2;
    const int m = mb + (t & 63);
    const int h = hb + (t >> 6);
    const float* wr = W1 + h * 128 + 64;
    float acc = 0.f;
#pragma unroll
    for (int d = 0; d < 64; ++d) acc = fmaf(wr[d], k[(d << 11) + m], acc);
    tile[((t & 63) << 2) + (t >> 6)] = acc;
    __syncthreads();
    kp[((mb + (t >> 2)) << 6) + hb + (t & 3)] = tile[t];
  }
}

// ---------------- K2 v3: register-tiled scores, h-chunked LDS ----------------
// Grid 512 = 16 q-tiles(64q) x 32 k-tiles(64k). Block 256 thr, 4x4 thread tile.
// LDS: two h-chunks of 32 -> qS/kS 64 rows x 8 f4 = 8 KB each = 16 KB total
// -> 4 blocks/CU (vs 2 at 32 KB), 16 waves/CU: doubles latency hiding.
// Swizzle col' = c ^ ((row>>2)&7): q-frag reads conflict-free (4 distinct
// slots), k-frag reads 2-way (free), staging writes at uniform 8 f4/slot floor.
__global__ __launch_bounds__(256, 4) void k2_scores(
    const float* __restrict__ qp, const float* __restrict__ kp,
    const float* __restrict__ W2, const float* __restrict__ b2p,
    float* __restrict__ scores, float* __restrict__ lpart)
{
  __shared__ float4 qS[512];          // 64q x 8 f4 (h-chunk of 32)
  __shared__ float4 kS[512];          // 64k x 8 f4
  const int t = threadIdx.x;
  const int qt = blockIdx.x >> 5;
  const int kt = blockIdx.x & 31;
  const int q0b = qt << 6, k0b = kt << 6;
  const float4* qp4 = (const float4*)qp;
  const float4* kp4 = (const float4*)kp;

  const int lane = t & 63, wave = t >> 6;
  const int lq = lane >> 4, lk = lane & 15;
  const int ql0 = (wave << 4) + (lq << 2);   // block-local q row base
  const int sq = ((wave << 2) | lq) & 7;     // (ql0>>2)&7
  const int kl0 = lk << 2;
  const int sk = lk & 7;                     // (kl0>>2)&7
  const float4* w24 = (const float4*)W2;     // uniform -> s_load

  float4 acc0 = {0,0,0,0}, acc1 = {0,0,0,0};
  float4 acc2 = {0,0,0,0}, acc3 = {0,0,0,0}; // accI = q-row I x k j=0..3

  for (int ch = 0; ch < 2; ++ch) {
    if (ch) __syncthreads();
#pragma unroll
    for (int i = 0; i < 2; ++i) {     // stage 64x8 f4 per array, coalesced
      const int idx = (i << 8) + t;   // 0..511
      const int row = idx >> 3, c = idx & 7;
      const int cs = c ^ ((row >> 2) & 7);
      qS[(row << 3) + cs] = qp4[((q0b + row) << 4) + (ch << 3) + c];
      kS[(row << 3) + cs] = kp4[((k0b + row) << 4) + (ch << 3) + c];
    }
    __syncthreads();
#pragma unroll
    for (int h4 = 0; h4 < 8; ++h4) {
      const float4 wv = w24[(ch << 3) + h4];
      const int qc = h4 ^ sq, kc = h4 ^ sk;
      const float4 q0f = qS[((ql0 + 0) << 3) + qc];
      const float4 q1f = qS[((ql0 + 1) << 3) + qc];
      const float4 q2f = qS[((ql0 + 2) << 3) + qc];
      const float4 q3f = qS[((ql0 + 3) << 3) + qc];
      const float4 k0f = kS[((kl0 + 0) << 3) + kc];
      const float4 k1f = kS[((kl0 + 1) << 3) + kc];
      const float4 k2f = kS[((kl0 + 2) << 3) + kc];
      const float4 k3f = kS[((kl0 + 3) << 3) + kc];
#define HC(C)                                                        \
      acc0.x = fmaf(wv.C, fmaxf(q0f.C + k0f.C, 0.f), acc0.x);        \
      acc0.y = fmaf(wv.C, fmaxf(q0f.C + k1f.C, 0.f), acc0.y);        \
      acc0.z = fmaf(wv.C, fmaxf(q0f.C + k2f.C, 0.f), acc0.z);        \
      acc0.w = fmaf(wv.C, fmaxf(q0f.C + k3f.C, 0.f), acc0.w);        \
      acc1.x = fmaf(wv.C, fmaxf(q1f.C + k0f.C, 0.f), acc1.x);        \
      acc1.y = fmaf(wv.C, fmaxf(q1f.C + k1f.C, 0.f), acc1.y);        \
      acc1.z = fmaf(wv.C, fmaxf(q1f.C + k2f.C, 0.f), acc1.z);        \
      acc1.w = fmaf(wv.C, fmaxf(q1f.C + k3f.C, 0.f), acc1.w);        \
      acc2.x = fmaf(wv.C, fmaxf(q2f.C + k0f.C, 0.f), acc2.x);        \
      acc2.y = fmaf(wv.C, fmaxf(q2f.C + k1f.C, 0.f), acc2.y);        \
      acc2.z = fmaf(wv.C, fmaxf(q2f.C + k2f.C, 0.f), acc2.z);        \
      acc2.w = fmaf(wv.C, fmaxf(q2f.C + k3f.C, 0.f), acc2.w);        \
      acc3.x = fmaf(wv.C, fmaxf(q3f.C + k0f.C, 0.f), acc3.x);        \
      acc3.y = fmaf(wv.C, fmaxf(q3f.C + k1f.C, 0.f), acc3.y);        \
      acc3.z = fmaf(wv.C, fmaxf(q3f.C + k2f.C, 0.f), acc3.z);        \
      acc3.w = fmaf(wv.C, fmaxf(q3f.C + k3f.C, 0.f), acc3.w);
      HC(x) HC(y) HC(z) HC(w)
#undef HC
    }
  }

  const float b2v = b2p[0];
  float4* sc4 = (float4*)scores;
  const int kcol = (k0b >> 2) + lk;
#define ROW_OUT(I, ACC) {                                            \
    float4 s = ACC;                                                  \
    s.x += b2v; s.y += b2v; s.z += b2v; s.w += b2v;                  \
    sc4[((q0b + ql0 + I) << 9) + kcol] = s;                          \
    float e = __expf(s.x) + __expf(s.y) + __expf(s.z) + __expf(s.w); \
    e += __shfl_xor(e, 1); e += __shfl_xor(e, 2);                    \
    e += __shfl_xor(e, 4); e += __shfl_xor(e, 8);                    \
    if (lk == 0) lpart[(kt << 10) + q0b + ql0 + I] = e; }
  ROW_OUT(0, acc0) ROW_OUT(1, acc1) ROW_OUT(2, acc2) ROW_OUT(3, acc3)
#undef ROW_OUT
}

// ---------------- K3: partial PV. part[ms][n][d] = sum_{m in split} p*V ------
__global__ __launch_bounds__(256, 2) void k3_pv(
    const float* __restrict__ scores, const float* __restrict__ v,
    float* __restrict__ part)
{
  __shared__ float4 pS4[1024];        // 64n x 16f4 (exp(scores))
  __shared__ float4 vtS4[1024];       // 64m x 16f4 transposed V, swizzled
  float* vtSf = (float*)vtS4;
  const int t = threadIdx.x;
  const int nt = blockIdx.x >> 5;
  const int ms = blockIdx.x & 31;
  const int n0b = nt << 6;
  const int mc4 = ms << 4;

  const float4* s4 = (const float4*)scores;
  const float4* v4 = (const float4*)v;
#pragma unroll
  for (int i = 0; i < 4; ++i) {       // stage p = exp(scores) tile
    const int idx = (i << 8) + t;
    const int n = idx >> 4, c = idx & 15;
    float4 val = s4[((n0b + n) << 9) + mc4 + c];
    val.x = __expf(val.x); val.y = __expf(val.y);
    val.z = __expf(val.z); val.w = __expf(val.w);
    pS4[(n << 4) + c] = val;
  }
#pragma unroll
  for (int i = 0; i < 4; ++i) {       // stage V chunk transposed
    const int idx = (i << 8) + t;
    const int dd = idx >> 4, c = idx & 15;
    const float4 val = v4[(dd << 9) + mc4 + c];
    const int co = (((dd >> 2) ^ c) << 2) + (dd & 3);
    vtSf[(c << 8) + co] = val.x;
    vtSf[(c << 8) + 64 + co] = val.y;
    vtSf[(c << 8) + 128 + co] = val.z;
    vtSf[(c << 8) + 192 + co] = val.w;
  }
  __syncthreads();

  const int tn = t >> 3, td = t & 7;
  const int n0l = tn << 1, n1l = n0l + 1;
  float4 acc00 = {0,0,0,0}, acc01 = {0,0,0,0};
  float4 acc10 = {0,0,0,0}, acc11 = {0,0,0,0};

#define PV_STEP(J, AC) {                                       \
    const float4 b0 = vtS4[(m4 << 6) + (J << 4) + c0];         \
    const float4 b1 = vtS4[(m4 << 6) + (J << 4) + (c0 ^ 8)];   \
    acc00.x = fmaf(a0.AC, b0.x, acc00.x);                      \
    acc00.y = fmaf(a0.AC, b0.y, acc00.y);                      \
    acc00.z = fmaf(a0.AC, b0.z, acc00.z);                      \
    acc00.w = fmaf(a0.AC, b0.w, acc00.w);                      \
    acc01.x = fmaf(a0.AC, b1.x, acc01.x);                      \
    acc01.y = fmaf(a0.AC, b1.y, acc01.y);                      \
    acc01.z = fmaf(a0.AC, b1.z, acc01.z);                      \
    acc01.w = fmaf(a0.AC, b1.w, acc01.w);                      \
    acc10.x = fmaf(a1.AC, b0.x, acc10.x);                      \
    acc10.y = fmaf(a1.AC, b0.y, acc10.y);                      \
    acc10.z = fmaf(a1.AC, b0.z, acc10.z);                      \
    acc10.w = fmaf(a1.AC, b0.w, acc10.w);                      \
    acc11.x = fmaf(a1.AC, b1.x, acc11.x);                      \
    acc11.y = fmaf(a1.AC, b1.y, acc11.y);                      \
    acc11.z = fmaf(a1.AC, b1.z, acc11.z);                      \
    acc11.w = fmaf(a1.AC, b1.w, acc11.w);                      \
  }

#pragma unroll
  for (int m4 = 0; m4 < 16; ++m4) {
    const float4 a0 = pS4[(n0l << 4) + m4];
    const float4 a1 = pS4[(n1l << 4) + m4];
    const int c0 = td ^ m4;
    PV_STEP(0, x) PV_STEP(1, y) PV_STEP(2, z) PV_STEP(3, w)
  }
#undef PV_STEP

  float4* part4 = (float4*)part;
  const int pb0 = (ms << 14) + ((n0b + n0l) << 4);
  const int pb1 = (ms << 14) + ((n0b + n1l) << 4);
  part4[pb0 + td] = acc00;
  part4[pb0 + td + 8] = acc01;
  part4[pb1 + td] = acc10;
  part4[pb1 + td + 8] = acc11;
}

// ---------------- K4: reduce partials, divide by l, transpose-store out -------
__global__ __launch_bounds__(256) void k4_reduce(
    const float* __restrict__ part, const float* __restrict__ lpart,
    float* __restrict__ out)
{
  __shared__ float oS[256];
  const int t = threadIdx.x;
  const int nb = blockIdx.x << 2;     // 256 blocks x 4 n
  const int nl = t >> 6, d = t & 63;
  const int n = nb + nl;
  float sum = 0.f;
#pragma unroll
  for (int ms = 0; ms < 32; ++ms)
    sum += part[(ms << 16) + (n << 6) + d];
  float l = 0.f;
#pragma unroll
  for (int kt = 0; kt < 32; ++kt)
    l += lpart[(kt << 10) + n];
  oS[(nl << 6) + d] = sum / l;
  __syncthreads();
  const int d2 = t >> 2, n2 = t & 3;
  out[(d2 << 10) + nb + n2] = oS[(n2 << 6) + d2];
}

extern "C" void kernel_launch(void* const* d_in, const int* in_sizes, int n_in,
                              void* d_out, int out_size, void* d_ws, size_t ws_size,
                              hipStream_t stream) {
  const float* query = (const float*)d_in[0];
  const float* key   = (const float*)d_in[1];
  const float* value = (const float*)d_in[2];
  const float* W1    = (const float*)d_in[3];
  const float* b1    = (const float*)d_in[4];
  const float* W2    = (const float*)d_in[5];
  const float* b2    = (const float*)d_in[6];

  float* out    = (float*)d_out;       // (1,64,1024)
  float* scores = out + 65536;         // (1,1024,2048)

  float* ws    = (float*)d_ws;
  float* qp    = ws;                   // 1024*64
  float* kp    = ws + 65536;           // 2048*64
  float* lpart = ws + 196608;          // 32 x 1024
  float* part  = ws + 229376;          // 32 x 1024 x 64

  k1_proj<<<768, 256, 0, stream>>>(query, key, W1, b1, qp, kp);
  k2_scores<<<512, 256, 0, stream>>>(qp, kp, W2, b2, scores, lpart);
  k3_pv<<<512, 256, 0, stream>>>(scores, value, part);
  k4_reduce<<<256, 256, 0, stream>>>(part, lpart, out);
}

// Round 9
// 98.983 us; speedup vs baseline: 2.3232x; 1.7931x over previous
//
#include <hip/hip_runtime.h>

// Problem: d=64, nq=1024, nk=2048, h=64.
// R5-proven 4-kernel pipeline (99.9 us). Measured context:
//  - Harness fixed overhead ~90 us/iter: 268 MB ws 0xAA poison fill (42.7 us
//    @ ~80% HBM peak) + d_out fill + 7 input restores + ~13 dispatch gaps.
//  - Our 4 kernels total ~10 us.
//  - R7: cooperative fusion = 140 us (grid.sync cost) — never again.
//  - R8: __launch_bounds__(256,4) on k2 capped VGPRs at 64 -> scratch spill,
//    321 MB HBM traffic, 93 us. Keep (256,2); never shrink VGPR budget
//    below the live set (~80 regs here).
// ws layout (floats): qp[1024][64] @0, kp[2048][64] @65536,
//   lpart[32][1024] @196608, part[32][1024][64] @229376
// scores lives in d_out (out[65536] then scores[1024*2048]).

// ---------------- K1: projections ----------------
__global__ __launch_bounds__(256) void k1_proj(
    const float* __restrict__ q, const float* __restrict__ k,
    const float* __restrict__ W1, const float* __restrict__ b1,
    float* __restrict__ qp, float* __restrict__ kp)
{
  __shared__ float tile[256];
  const int t = threadIdx.x;
  const int b = blockIdx.x;
  if (b < 256) {                      // qp: 16 n-tiles x 16 h-tiles
    const int nb = (b & 15) << 6;
    const int hb = (b >> 4) << 2;
    const int n = nb + (t & 63);
    const int h = hb + (t >> 6);      // wave-uniform
    const float* wr = W1 + h * 128;
    float acc = b1[h];
#pragma unroll
    for (int d = 0; d < 64; ++d) acc = fmaf(wr[d], q[(d << 10) + n], acc);
    tile[((t & 63) << 2) + (t >> 6)] = acc;
    __syncthreads();
    qp[((nb + (t >> 2)) << 6) + hb + (t & 3)] = tile[t];
  } else {                            // kp: 32 m-tiles x 16 h-tiles
    const int b2 = b - 256;
    const int mb = (b2 & 31) << 6;
    const int hb = (b2 >> 5) << 2;
    const int m = mb + (t & 63);
    const int h = hb + (t >> 6);
    const float* wr = W1 + h * 128 + 64;
    float acc = 0.f;
#pragma unroll
    for (int d = 0; d < 64; ++d) acc = fmaf(wr[d], k[(d << 11) + m], acc);
    tile[((t & 63) << 2) + (t >> 6)] = acc;
    __syncthreads();
    kp[((mb + (t >> 2)) << 6) + hb + (t & 3)] = tile[t];
  }
}

// ---------------- K2 v2 (R5-proven): register-tiled scores ----------------
// Grid 512 = 16 q-tiles(64q) x 32 k-tiles(64k). Block 256 thr, 4x4 thread
// tile. LDS 32 KB, __launch_bounds__(256,2): VGPR budget 256 -> no spill.
__global__ __launch_bounds__(256, 2) void k2_scores(
    const float* __restrict__ qp, const float* __restrict__ kp,
    const float* __restrict__ W2, const float* __restrict__ b2p,
    float* __restrict__ scores, float* __restrict__ lpart)
{
  __shared__ float4 qS[1024];         // 64q x 16 f4, col ^= ((row>>2)&15)
  __shared__ float4 kS[1024];         // 64k x 16 f4, same swizzle
  const int t = threadIdx.x;
  const int qt = blockIdx.x >> 5;
  const int kt = blockIdx.x & 31;
  const int q0b = qt << 6, k0b = kt << 6;
  const float4* qp4 = (const float4*)qp;
  const float4* kp4 = (const float4*)kp;
#pragma unroll
  for (int i = 0; i < 4; ++i) {       // stage both tiles, coalesced
    const int idx = (i << 8) + t;
    const int row = idx >> 4, c = idx & 15;
    const int cs = c ^ ((row >> 2) & 15);
    qS[(row << 4) + cs] = qp4[((q0b + row) << 4) + c];
    kS[(row << 4) + cs] = kp4[((k0b + row) << 4) + c];
  }
  __syncthreads();

  const int lane = t & 63, wave = t >> 6;
  const int lq = lane >> 4, lk = lane & 15;
  const int ql0 = (wave << 4) + (lq << 2);   // block-local q row base
  const int sq = (wave << 2) | lq;           // ((ql0>>2)&15)
  const int kl0 = lk << 2;
  const float4* w24 = (const float4*)W2;     // uniform -> s_load

  float4 acc0 = {0,0,0,0}, acc1 = {0,0,0,0};
  float4 acc2 = {0,0,0,0}, acc3 = {0,0,0,0}; // accI = q-row I x k j=0..3

#pragma unroll 4
  for (int h4 = 0; h4 < 16; ++h4) {
    const float4 wv = w24[h4];
    const int qc = h4 ^ sq, kc = h4 ^ lk;
    const float4 q0f = qS[((ql0 + 0) << 4) + qc];
    const float4 q1f = qS[((ql0 + 1) << 4) + qc];
    const float4 q2f = qS[((ql0 + 2) << 4) + qc];
    const float4 q3f = qS[((ql0 + 3) << 4) + qc];
    const float4 k0f = kS[((kl0 + 0) << 4) + kc];
    const float4 k1f = kS[((kl0 + 1) << 4) + kc];
    const float4 k2f = kS[((kl0 + 2) << 4) + kc];
    const float4 k3f = kS[((kl0 + 3) << 4) + kc];
#define HC(C)                                                        \
    acc0.x = fmaf(wv.C, fmaxf(q0f.C + k0f.C, 0.f), acc0.x);          \
    acc0.y = fmaf(wv.C, fmaxf(q0f.C + k1f.C, 0.f), acc0.y);          \
    acc0.z = fmaf(wv.C, fmaxf(q0f.C + k2f.C, 0.f), acc0.z);          \
    acc0.w = fmaf(wv.C, fmaxf(q0f.C + k3f.C, 0.f), acc0.w);          \
    acc1.x = fmaf(wv.C, fmaxf(q1f.C + k0f.C, 0.f), acc1.x);          \
    acc1.y = fmaf(wv.C, fmaxf(q1f.C + k1f.C, 0.f), acc1.y);          \
    acc1.z = fmaf(wv.C, fmaxf(q1f.C + k2f.C, 0.f), acc1.z);          \
    acc1.w = fmaf(wv.C, fmaxf(q1f.C + k3f.C, 0.f), acc1.w);          \
    acc2.x = fmaf(wv.C, fmaxf(q2f.C + k0f.C, 0.f), acc2.x);          \
    acc2.y = fmaf(wv.C, fmaxf(q2f.C + k1f.C, 0.f), acc2.y);          \
    acc2.z = fmaf(wv.C, fmaxf(q2f.C + k2f.C, 0.f), acc2.z);          \
    acc2.w = fmaf(wv.C, fmaxf(q2f.C + k3f.C, 0.f), acc2.w);          \
    acc3.x = fmaf(wv.C, fmaxf(q3f.C + k0f.C, 0.f), acc3.x);          \
    acc3.y = fmaf(wv.C, fmaxf(q3f.C + k1f.C, 0.f), acc3.y);          \
    acc3.z = fmaf(wv.C, fmaxf(q3f.C + k2f.C, 0.f), acc3.z);          \
    acc3.w = fmaf(wv.C, fmaxf(q3f.C + k3f.C, 0.f), acc3.w);
    HC(x) HC(y) HC(z) HC(w)
#undef HC
  }

  const float b2v = b2p[0];
  float4* sc4 = (float4*)scores;
  const int kcol = (k0b >> 2) + lk;
#define ROW_OUT(I, ACC) {                                            \
    float4 s = ACC;                                                  \
    s.x += b2v; s.y += b2v; s.z += b2v; s.w += b2v;                  \
    sc4[((q0b + ql0 + I) << 9) + kcol] = s;                          \
    float e = __expf(s.x) + __expf(s.y) + __expf(s.z) + __expf(s.w); \
    e += __shfl_xor(e, 1); e += __shfl_xor(e, 2);                    \
    e += __shfl_xor(e, 4); e += __shfl_xor(e, 8);                    \
    if (lk == 0) lpart[(kt << 10) + q0b + ql0 + I] = e; }
  ROW_OUT(0, acc0) ROW_OUT(1, acc1) ROW_OUT(2, acc2) ROW_OUT(3, acc3)
#undef ROW_OUT
}

// ---------------- K3: partial PV. part[ms][n][d] = sum_{m in split} p*V ------
__global__ __launch_bounds__(256, 2) void k3_pv(
    const float* __restrict__ scores, const float* __restrict__ v,
    float* __restrict__ part)
{
  __shared__ float4 pS4[1024];        // 64n x 16f4 (exp(scores))
  __shared__ float4 vtS4[1024];       // 64m x 16f4 transposed V, swizzled
  float* vtSf = (float*)vtS4;
  const int t = threadIdx.x;
  const int nt = blockIdx.x >> 5;
  const int ms = blockIdx.x & 31;
  const int n0b = nt << 6;
  const int mc4 = ms << 4;

  const float4* s4 = (const float4*)scores;
  const float4* v4 = (const float4*)v;
#pragma unroll
  for (int i = 0; i < 4; ++i) {       // stage p = exp(scores) tile
    const int idx = (i << 8) + t;
    const int n = idx >> 4, c = idx & 15;
    float4 val = s4[((n0b + n) << 9) + mc4 + c];
    val.x = __expf(val.x); val.y = __expf(val.y);
    val.z = __expf(val.z); val.w = __expf(val.w);
    pS4[(n << 4) + c] = val;
  }
#pragma unroll
  for (int i = 0; i < 4; ++i) {       // stage V chunk transposed
    const int idx = (i << 8) + t;
    const int dd = idx >> 4, c = idx & 15;
    const float4 val = v4[(dd << 9) + mc4 + c];
    const int co = (((dd >> 2) ^ c) << 2) + (dd & 3);
    vtSf[(c << 8) + co] = val.x;
    vtSf[(c << 8) + 64 + co] = val.y;
    vtSf[(c << 8) + 128 + co] = val.z;
    vtSf[(c << 8) + 192 + co] = val.w;
  }
  __syncthreads();

  const int tn = t >> 3, td = t & 7;
  const int n0l = tn << 1, n1l = n0l + 1;
  float4 acc00 = {0,0,0,0}, acc01 = {0,0,0,0};
  float4 acc10 = {0,0,0,0}, acc11 = {0,0,0,0};

#define PV_STEP(J, AC) {                                       \
    const float4 b0 = vtS4[(m4 << 6) + (J << 4) + c0];         \
    const float4 b1 = vtS4[(m4 << 6) + (J << 4) + (c0 ^ 8)];   \
    acc00.x = fmaf(a0.AC, b0.x, acc00.x);                      \
    acc00.y = fmaf(a0.AC, b0.y, acc00.y);                      \
    acc00.z = fmaf(a0.AC, b0.z, acc00.z);                      \
    acc00.w = fmaf(a0.AC, b0.w, acc00.w);                      \
    acc01.x = fmaf(a0.AC, b1.x, acc01.x);                      \
    acc01.y = fmaf(a0.AC, b1.y, acc01.y);                      \
    acc01.z = fmaf(a0.AC, b1.z, acc01.z);                      \
    acc01.w = fmaf(a0.AC, b1.w, acc01.w);                      \
    acc10.x = fmaf(a1.AC, b0.x, acc10.x);                      \
    acc10.y = fmaf(a1.AC, b0.y, acc10.y);                      \
    acc10.z = fmaf(a1.AC, b0.z, acc10.z);                      \
    acc10.w = fmaf(a1.AC, b0.w, acc10.w);                      \
    acc11.x = fmaf(a1.AC, b1.x, acc11.x);                      \
    acc11.y = fmaf(a1.AC, b1.y, acc11.y);                      \
    acc11.z = fmaf(a1.AC, b1.z, acc11.z);                      \
    acc11.w = fmaf(a1.AC, b1.w, acc11.w);                      \
  }

#pragma unroll
  for (int m4 = 0; m4 < 16; ++m4) {
    const float4 a0 = pS4[(n0l << 4) + m4];
    const float4 a1 = pS4[(n1l << 4) + m4];
    const int c0 = td ^ m4;
    PV_STEP(0, x) PV_STEP(1, y) PV_STEP(2, z) PV_STEP(3, w)
  }
#undef PV_STEP

  float4* part4 = (float4*)part;
  const int pb0 = (ms << 14) + ((n0b + n0l) << 4);
  const int pb1 = (ms << 14) + ((n0b + n1l) << 4);
  part4[pb0 + td] = acc00;
  part4[pb0 + td + 8] = acc01;
  part4[pb1 + td] = acc10;
  part4[pb1 + td + 8] = acc11;
}

// ---------------- K4: reduce partials, divide by l, transpose-store out -------
__global__ __launch_bounds__(256) void k4_reduce(
    const float* __restrict__ part, const float* __restrict__ lpart,
    float* __restrict__ out)
{
  __shared__ float oS[256];
  const int t = threadIdx.x;
  const int nb = blockIdx.x << 2;     // 256 blocks x 4 n
  const int nl = t >> 6, d = t & 63;
  const int n = nb + nl;
  float sum = 0.f;
#pragma unroll
  for (int ms = 0; ms < 32; ++ms)
    sum += part[(ms << 16) + (n << 6) + d];
  float l = 0.f;
#pragma unroll
  for (int kt = 0; kt < 32; ++kt)
    l += lpart[(kt << 10) + n];
  oS[(nl << 6) + d] = sum / l;
  __syncthreads();
  const int d2 = t >> 2, n2 = t & 3;
  out[(d2 << 10) + nb + n2] = oS[(n2 << 6) + d2];
}

extern "C" void kernel_launch(void* const* d_in, const int* in_sizes, int n_in,
                              void* d_out, int out_size, void* d_ws, size_t ws_size,
                              hipStream_t stream) {
  const float* query = (const float*)d_in[0];
  const float* key   = (const float*)d_in[1];
  const float* value = (const float*)d_in[2];
  const float* W1    = (const float*)d_in[3];
  const float* b1    = (const float*)d_in[4];
  const float* W2    = (const float*)d_in[5];
  const float* b2    = (const float*)d_in[6];

  float* out    = (float*)d_out;       // (1,64,1024)
  float* scores = out + 65536;         // (1,1024,2048)

  float* ws    = (float*)d_ws;
  float* qp    = ws;                   // 1024*64
  float* kp    = ws + 65536;           // 2048*64
  float* lpart = ws + 196608;          // 32 x 1024
  float* part  = ws + 229376;          // 32 x 1024 x 64

  k1_proj<<<768, 256, 0, stream>>>(query, key, W1, b1, qp, kp);
  k2_scores<<<512, 256, 0, stream>>>(qp, kp, W2, b2, scores, lpart);
  k3_pv<<<512, 256, 0, stream>>>(scores, value, part);
  k4_reduce<<<256, 256, 0, stream>>>(part, lpart, out);
}